// Round 6
// baseline (103.372 us; speedup 1.0000x reference)
//
#include <hip/hip_runtime.h>

typedef unsigned int uint;
typedef unsigned short ushort;
typedef __attribute__((ext_vector_type(8))) short short8;
typedef __attribute__((ext_vector_type(4))) float f32x4;

#define B_   512
#define V_   256
#define M_   128
#define H_   512
#define T_   16
#define KTOT 34816   // V_*M_ + M_*T_

// ---------------- helpers ----------------
__device__ __forceinline__ ushort f2bf(float f) {
  uint u = __builtin_bit_cast(uint, f);
  u += 0x7fffu + ((u >> 16) & 1u);   // RNE
  return (ushort)(u >> 16);
}

// sigma-swizzle: within each 32-element (64B) k-group, XOR the 16B-chunk index
// with ((row>>1)&3). A's writer (prep) applies it; gemm1 reads it back.
__device__ __forceinline__ int swz_k(int k, int row) {
  return (k & ~31) | (((((k >> 3) & 3) ^ ((row >> 1) & 3)) << 3)) | (k & 7);
}

// ---------------- kernel 1: per-batch prep ----------------
__global__ __launch_bounds__(256) void prep_kernel(
    const float* __restrict__ x, const float* __restrict__ mem,
    const int* __restrict__ timings, const float* __restrict__ msurp,
    const float* __restrict__ b1,
    ushort* __restrict__ A, float* __restrict__ h_pre)
{
  const int b = blockIdx.x, tid = threadIdx.x;
  __shared__ int s_t[M_];
  __shared__ int s_row[M_];
  __shared__ int s_st[M_];
  __shared__ int s_idx;

  if (tid < 64) {
    float v0 = msurp[b * M_ + tid];
    float v1 = msurp[b * M_ + tid + 64];
    float v; int i;
    if (v1 < v0) { v = v1; i = tid + 64; } else { v = v0; i = tid; }
    #pragma unroll
    for (int off = 32; off > 0; off >>= 1) {
      float ov = __shfl_down(v, off);
      int   oi = __shfl_down(i, off);
      if (ov < v || (ov == v && oi < i)) { v = ov; i = oi; }
    }
    if (tid == 0) s_idx = i;
  }
  __syncthreads();
  const int idx = s_idx;

  if (tid < M_) {
    int t = timings[b * M_ + tid] + 1;
    if (tid == idx) t = 0;
    s_t[tid] = t;
  }
  // h_pre init = b1 (consumed only by the atomic fallback path)
  h_pre[(size_t)b * H_ + tid]       = b1[tid];
  h_pre[(size_t)b * H_ + 256 + tid] = b1[256 + tid];
  __syncthreads();

  if (tid < M_) {
    const int t = s_t[tid];
    int r = 0;
    for (int j = 0; j < M_; ++j) {
      int tj = s_t[j];
      r += (tj < t || (tj == t && j < tid)) ? 1 : 0;
    }
    s_row[r] = tid;   // order[r] = tid
    s_st[r]  = t;     // sorted_t[r]
  }
  __syncthreads();

  // bits region (k >= 32768), swizzled writes
  if (tid < M_) {
    const int t = s_st[tid];
    uint p[8];
    #pragma unroll
    for (int h = 0; h < 8; ++h) {
      uint lo = ((t >> (2 * h)) & 1) ? 0x3F80u : 0u;
      uint hi = ((t >> (2 * h + 1)) & 1) ? 0x3F80u : 0u;
      p[h] = lo | (hi << 16);
    }
    const int k0 = V_ * M_ + tid * T_;
    uint4 w0; w0.x = p[0]; w0.y = p[1]; w0.z = p[2]; w0.w = p[3];
    uint4 w1; w1.x = p[4]; w1.y = p[5]; w1.z = p[6]; w1.w = p[7];
    *(uint4*)(A + (size_t)b * KTOT + swz_k(k0, b))     = w0;
    *(uint4*)(A + (size_t)b * KTOT + swz_k(k0 + 8, b)) = w1;
  }

  // gather rows, swizzled writes (8B pieces stay within one 16B chunk)
  const int lane = tid & 63, sub = tid >> 6;
  for (int it = 0; it < 32; ++it) {
    const int slot = it * 4 + sub;
    const int rowm = s_row[slot];
    const float* src = (rowm == idx) ? (x + (size_t)b * V_)
                                     : (mem + ((size_t)b * M_ + rowm) * V_);
    f32x4 v = *(const f32x4*)(src + lane * 4);
    uint2 o;
    o.x = (uint)f2bf(v[0]) | ((uint)f2bf(v[1]) << 16);
    o.y = (uint)f2bf(v[2]) | ((uint)f2bf(v[3]) << 16);
    const int k = slot * V_ + lane * 4;
    *(uint2*)(A + (size_t)b * KTOT + swz_k(k, b)) = o;
  }
}

// ---------------- kernel 2: split-K bf16 MFMA GEMM, counted-vmcnt pipeline ----------------
// A: global_load_lds (3 LDS buffers).  B: reg-stage raw f32 W1 -> bf16 -> swizzled ds_write (2 buffers).
// Exactly 10 VMEM ops issued per iteration (8 loadB dwords + 2 gld_lds):
//   entry wait vmcnt(10) retires stageA(c) only; loads for c+1/c+2 stay in flight.
#define BM 256
#define BN 128
#define SPLITK 64
#define KCH 544
#define NCHU 17

#define GLD16(g, l) __builtin_amdgcn_global_load_lds( \
  (const __attribute__((address_space(1))) void*)(g), \
  (__attribute__((address_space(3))) void*)(l), 16, 0, 0)

template<bool USE_ATOMIC>
__global__ __launch_bounds__(512, 4) void gemm1_kernel(
    const ushort* __restrict__ A, const float* __restrict__ W1,
    float* __restrict__ dst)   // h_pre (atomic) or partials P[SPLITK][512][512]
{
  __shared__ __align__(16) ushort As[3][BM * 32];   // 48 KB
  __shared__ __align__(16) ushort Bs[2][BN * 32];   // 16 KB

  const int bid  = blockIdx.x;
  const int tile = bid & 7;      // 2 m-tiles x 4 n-tiles
  const int sk   = bid >> 3;     // 0..63
  const int b0   = (tile >> 2) * BM;
  const int n0   = (tile & 3) * BN;
  const int tid  = threadIdx.x, wave = tid >> 6, lane = tid & 63;
  const int wm   = wave >> 1;
  const int wn   = wave & 1;
  const long kb0 = (long)sk * KCH;

  f32x4 acc[4][4];
  #pragma unroll
  for (int i = 0; i < 4; ++i)
    #pragma unroll
    for (int j = 0; j < 4; ++j) acc[i][j] = (f32x4)0.f;

  // A staging (global_load_lds, linear dest)
  const int ar  = wave * 32 + (lane >> 2);
  const int akk = (lane & 3) * 8;
  auto stageA = [&](int buf, int chunk) {
    const long kb = kb0 + (long)chunk * 32;
    GLD16(A + ((size_t)(b0 + ar))      * KTOT + kb + akk, &As[buf][(wave * 32) * 32]);
    GLD16(A + ((size_t)(b0 + ar + 16)) * KTOT + kb + akk, &As[buf][(wave * 32 + 16) * 32]);
  };

  // B staging: thread -> column n = n0+(tid&127), k-chunk kc = tid>>7 (8 k's)
  const int bn_  = tid & 127;
  const int bkc  = tid >> 7;                 // 0..3
  const float* w1p = W1 + (size_t)(kb0 + bkc * 8) * H_ + n0 + bn_;
  const int b_woff = bn_ * 32 + ((bkc ^ ((bn_ >> 1) & 3)) * 8);

  auto loadB = [&](float* r, int c) {
    const float* p = w1p + (size_t)c * 32 * H_;
    #pragma unroll
    for (int i = 0; i < 8; ++i) r[i] = p[(size_t)i * H_];
  };
  auto writeB = [&](const float* r, ushort* d) {
    uint4 o;
    o.x = (uint)f2bf(r[0]) | ((uint)f2bf(r[1]) << 16);
    o.y = (uint)f2bf(r[2]) | ((uint)f2bf(r[3]) << 16);
    o.z = (uint)f2bf(r[4]) | ((uint)f2bf(r[5]) << 16);
    o.w = (uint)f2bf(r[6]) | ((uint)f2bf(r[7]) << 16);
    *(uint4*)d = o;
  };

  // de-swizzle read offset for frag loads
  const int xo     = (((lane >> 4) ^ ((lane >> 1) & 3)) * 8);
  const int a_roff = (wm * 64 + (lane & 15)) * 32;
  const int b_roff = (wn * 64 + (lane & 15)) * 32;

  float brE[8], brO[8];

#define GITER(c, BRL, BRW, ISSUE, WRITE, VMC) do {                            \
    asm volatile("s_waitcnt vmcnt(" VMC ") lgkmcnt(0)" ::: "memory");         \
    __builtin_amdgcn_s_barrier();                                             \
    __builtin_amdgcn_sched_barrier(0);                                        \
    if (ISSUE) { loadB(BRL, (c) + 2); stageA(((c) + 2) % 3, (c) + 2); }       \
    const ushort* as_ = &As[(c) % 3][a_roff + xo];                            \
    const ushort* bs_ = &Bs[(c) & 1][b_roff + xo];                            \
    short8 af[4], bf[4];                                                      \
    _Pragma("unroll") for (int i = 0; i < 4; ++i) {                           \
      af[i] = *(const short8*)(as_ + i * 16 * 32);                            \
      bf[i] = *(const short8*)(bs_ + i * 16 * 32); }                          \
    _Pragma("unroll") for (int i = 0; i < 4; ++i)                             \
      _Pragma("unroll") for (int j = 0; j < 4; ++j)                           \
        acc[i][j] = __builtin_amdgcn_mfma_f32_16x16x32_bf16(af[i], bf[j],     \
                                                            acc[i][j], 0,0,0);\
    if (WRITE) writeB(BRW, &Bs[((c) + 1) & 1][b_woff]);                       \
  } while (0)

  // prologue: chunks 0,1 in flight; Bs[0] written (compiler inserts vmcnt for brE)
  loadB(brE, 0);
  stageA(0, 0);
  loadB(brO, 1);
  stageA(1, 1);
  writeB(brE, &Bs[0][b_woff]);

  #pragma unroll 1
  for (int cc = 0; cc < 14; cc += 2) {
    GITER(cc,     brE, brO, true, true, "10");
    GITER(cc + 1, brO, brE, true, true, "10");
  }
  GITER(14, brE, brO, true,  true,  "10");
  GITER(15, brO, brE, false, true,  "10");
  GITER(16, brE, brO, false, false, "0");
#undef GITER

  const int row0 = b0 + wm * 64 + (lane >> 4) * 4;
  const int col0 = n0 + wn * 64 + (lane & 15);
  if constexpr (USE_ATOMIC) {
    #pragma unroll
    for (int i = 0; i < 4; ++i)
      #pragma unroll
      for (int j = 0; j < 4; ++j)
        #pragma unroll
        for (int r = 0; r < 4; ++r)
          atomicAdd(&dst[(size_t)(row0 + i * 16 + r) * H_ + col0 + j * 16], acc[i][j][r]);
  } else {
    float* P = dst + (size_t)sk * (B_ * H_);
    #pragma unroll
    for (int i = 0; i < 4; ++i)
      #pragma unroll
      for (int j = 0; j < 4; ++j)
        #pragma unroll
        for (int r = 0; r < 4; ++r)
          P[(size_t)(row0 + i * 16 + r) * H_ + col0 + j * 16] = acc[i][j][r];
  }
}

// ---------------- kernel 3: fused reduce + relu + GEMM2 ----------------
// out[b][v] = b2[v] + sum_n relu(b1[n] + sum_sk P[sk][b][n]) * W2[n][v]
template<bool FROM_PARTIALS>
__global__ __launch_bounds__(256) void gemm2_kernel(
    const float* __restrict__ Pin, const float* __restrict__ b1,
    const float* __restrict__ W2, const float* __restrict__ b2,
    float* __restrict__ out)
{
  const int bb = blockIdx.x * 2;   // 256 blocks, 2 batch rows each
  const int v  = threadIdx.x;      // 0..255
  __shared__ float hs[2][H_];

  // build hs = relu(b1 + sum P) : each thread owns 4 h-elements (f32x4)
  {
    const int id  = v * 4;                 // 0..1020 over 2*512
    const int row = id >> 9, col = id & 511;
    f32x4 s;
    if constexpr (FROM_PARTIALS) {
      s = *(const f32x4*)(b1 + col);
      #pragma unroll 4
      for (int sk = 0; sk < SPLITK; ++sk)
        s += *(const f32x4*)(Pin + (size_t)sk * (B_ * H_) + (size_t)(bb + row) * H_ + col);
    } else {
      s = *(const f32x4*)(Pin + (size_t)(bb + row) * H_ + col);  // h_pre already has b1
    }
    f32x4 r;
    #pragma unroll
    for (int t = 0; t < 4; ++t) r[t] = fmaxf(s[t], 0.f);
    *(f32x4*)&hs[row][col] = r;
  }
  __syncthreads();

  float a0 = 0.f, a1 = 0.f;
  for (int j4 = 0; j4 < H_ / 4; ++j4) {
    f32x4 h0 = *(const f32x4*)&hs[0][j4 * 4];
    f32x4 h1 = *(const f32x4*)&hs[1][j4 * 4];
    #pragma unroll
    for (int t = 0; t < 4; ++t) {
      float w = W2[(size_t)(j4 * 4 + t) * V_ + v];
      a0 += h0[t] * w; a1 += h1[t] * w;
    }
  }
  const float bias = b2[v];
  out[(size_t)(bb + 0) * V_ + v] = a0 + bias;
  out[(size_t)(bb + 1) * V_ + v] = a1 + bias;
}

// ---------------- launch ----------------
extern "C" void kernel_launch(void* const* d_in, const int* in_sizes, int n_in,
                              void* d_out, int out_size, void* d_ws, size_t ws_size,
                              hipStream_t stream) {
  const float* x   = (const float*)d_in[0];
  const float* mem = (const float*)d_in[1];
  const int*   tim = (const int*)d_in[2];
  const float* msu = (const float*)d_in[3];
  const float* W1  = (const float*)d_in[5];
  const float* b1  = (const float*)d_in[6];
  const float* W2  = (const float*)d_in[7];
  const float* b2  = (const float*)d_in[8];
  float* out = (float*)d_out;

  char* ws = (char*)d_ws;
  const size_t abytes = (size_t)B_ * KTOT * 2;          // 35,651,584
  const size_t pbytes = (size_t)SPLITK * B_ * H_ * 4;   // 67,108,864
  const size_t hbytes = (size_t)B_ * H_ * 4;            // 1,048,576
  const bool partials = ws_size >= abytes + pbytes + hbytes;

  ushort* A_ws  = (ushort*)ws;
  float*  P     = (float*)(ws + abytes);
  float*  h_pre = partials ? (float*)(ws + abytes + pbytes)
                           : (float*)(ws + abytes);

  prep_kernel<<<B_, 256, 0, stream>>>(x, mem, tim, msu, b1, A_ws, h_pre);
  if (partials) {
    gemm1_kernel<false><<<8 * SPLITK, 512, 0, stream>>>(A_ws, W1, P);
    gemm2_kernel<true><<<B_ / 2, 256, 0, stream>>>(P, b1, W2, b2, out);
  } else {
    gemm1_kernel<true><<<8 * SPLITK, 512, 0, stream>>>(A_ws, W1, h_pre);
    gemm2_kernel<false><<<B_ / 2, 256, 0, stream>>>(h_pre, b1, W2, b2, out);
  }
}

// Round 7
// 76.255 us; speedup vs baseline: 1.3556x; 1.3556x over previous
//
#include <hip/hip_runtime.h>

typedef unsigned int uint;
typedef unsigned short ushort;
typedef __attribute__((ext_vector_type(8))) short short8;
typedef __attribute__((ext_vector_type(4))) float f32x4;

#define B_   512
#define V_   256
#define M_   128
#define H_   512
#define T_   16
#define KTOT 34816   // V_*M_ + M_*T_

// ---------------- helpers ----------------
__device__ __forceinline__ ushort f2bf(float f) {
  uint u = __builtin_bit_cast(uint, f);
  u += 0x7fffu + ((u >> 16) & 1u);   // RNE
  return (ushort)(u >> 16);
}
__device__ __forceinline__ float bf2f(ushort s) {
  return __builtin_bit_cast(float, ((uint)s) << 16);
}

// sigma-swizzle: within each 32-element (64B) k-group, XOR the 16B-chunk index
// with ((row>>1)&3). A's writer (prep) applies it; gemm1 reads it back.
__device__ __forceinline__ int swz_k(int k, int row) {
  return (k & ~31) | (((((k >> 3) & 3) ^ ((row >> 1) & 3)) << 3)) | (k & 7);
}

// ---------------- kernel 1: per-batch prep ----------------
__global__ __launch_bounds__(256) void prep_kernel(
    const float* __restrict__ x, const float* __restrict__ mem,
    const int* __restrict__ timings, const float* __restrict__ msurp,
    const float* __restrict__ b1,
    ushort* __restrict__ A, float* __restrict__ h_pre)
{
  const int b = blockIdx.x, tid = threadIdx.x;
  __shared__ int s_t[M_];
  __shared__ int s_row[M_];
  __shared__ int s_st[M_];
  __shared__ int s_idx;

  if (tid < 64) {
    float v0 = msurp[b * M_ + tid];
    float v1 = msurp[b * M_ + tid + 64];
    float v; int i;
    if (v1 < v0) { v = v1; i = tid + 64; } else { v = v0; i = tid; }
    #pragma unroll
    for (int off = 32; off > 0; off >>= 1) {
      float ov = __shfl_down(v, off);
      int   oi = __shfl_down(i, off);
      if (ov < v || (ov == v && oi < i)) { v = ov; i = oi; }
    }
    if (tid == 0) s_idx = i;
  }
  __syncthreads();
  const int idx = s_idx;

  if (tid < M_) {
    int t = timings[b * M_ + tid] + 1;
    if (tid == idx) t = 0;
    s_t[tid] = t;
  }
  // h_pre init = b1 (consumed only by the atomic fallback path)
  h_pre[(size_t)b * H_ + tid]       = b1[tid];
  h_pre[(size_t)b * H_ + 256 + tid] = b1[256 + tid];
  __syncthreads();

  if (tid < M_) {
    const int t = s_t[tid];
    int r = 0;
    for (int j = 0; j < M_; ++j) {
      int tj = s_t[j];
      r += (tj < t || (tj == t && j < tid)) ? 1 : 0;
    }
    s_row[r] = tid;   // order[r] = tid
    s_st[r]  = t;     // sorted_t[r]
  }
  __syncthreads();

  // bits region (k >= 32768), swizzled writes
  if (tid < M_) {
    const int t = s_st[tid];
    uint p[8];
    #pragma unroll
    for (int h = 0; h < 8; ++h) {
      uint lo = ((t >> (2 * h)) & 1) ? 0x3F80u : 0u;
      uint hi = ((t >> (2 * h + 1)) & 1) ? 0x3F80u : 0u;
      p[h] = lo | (hi << 16);
    }
    const int k0 = V_ * M_ + tid * T_;
    uint4 w0; w0.x = p[0]; w0.y = p[1]; w0.z = p[2]; w0.w = p[3];
    uint4 w1; w1.x = p[4]; w1.y = p[5]; w1.z = p[6]; w1.w = p[7];
    *(uint4*)(A + (size_t)b * KTOT + swz_k(k0, b))     = w0;
    *(uint4*)(A + (size_t)b * KTOT + swz_k(k0 + 8, b)) = w1;
  }

  // gather rows, swizzled writes (8B pieces stay within one 16B chunk)
  const int lane = tid & 63, sub = tid >> 6;
  for (int it = 0; it < 32; ++it) {
    const int slot = it * 4 + sub;
    const int rowm = s_row[slot];
    const float* src = (rowm == idx) ? (x + (size_t)b * V_)
                                     : (mem + ((size_t)b * M_ + rowm) * V_);
    f32x4 v = *(const f32x4*)(src + lane * 4);
    uint2 o;
    o.x = (uint)f2bf(v[0]) | ((uint)f2bf(v[1]) << 16);
    o.y = (uint)f2bf(v[2]) | ((uint)f2bf(v[3]) << 16);
    const int k = slot * V_ + lane * 4;
    *(uint2*)(A + (size_t)b * KTOT + swz_k(k, b)) = o;
  }
}

// ---------------- kernel 2: split-K bf16 MFMA GEMM, counted-vmcnt pipeline ----------------
// XCD-aligned swizzle: sk = (bid&7) + 8*(bid>>6), tile = (bid>>3)&7.
// The 8 tiles sharing one (A-slice, W1-slice) are consecutive bids with the same
// bid%8 -> same XCD, co-dispatched -> slice fetched into that XCD's L2 once.
#define BM 256
#define BN 128
#define SPLITK 64
#define KCH 544
#define NCHU 17

#define GLD16(g, l) __builtin_amdgcn_global_load_lds( \
  (const __attribute__((address_space(1))) void*)(g), \
  (__attribute__((address_space(3))) void*)(l), 16, 0, 0)

template<bool USE_ATOMIC>
__global__ __launch_bounds__(512, 4) void gemm1_kernel(
    const ushort* __restrict__ A, const float* __restrict__ W1,
    void* __restrict__ dstv)   // fp32 h_pre (atomic) or bf16 partials P[SPLITK][512][512]
{
  __shared__ __align__(16) ushort As[3][BM * 32];   // 48 KB
  __shared__ __align__(16) ushort Bs[2][BN * 32];   // 16 KB

  const int bid  = blockIdx.x;
  const int sk   = (bid & 7) | ((bid >> 6) << 3);   // 0..63
  const int tile = (bid >> 3) & 7;                  // 2 m-tiles x 4 n-tiles
  const int b0   = (tile >> 2) * BM;
  const int n0   = (tile & 3) * BN;
  const int tid  = threadIdx.x, wave = tid >> 6, lane = tid & 63;
  const int wm   = wave >> 1;
  const int wn   = wave & 1;
  const long kb0 = (long)sk * KCH;

  f32x4 acc[4][4];
  #pragma unroll
  for (int i = 0; i < 4; ++i)
    #pragma unroll
    for (int j = 0; j < 4; ++j) acc[i][j] = (f32x4)0.f;

  // A staging (global_load_lds, linear dest)
  const int ar  = wave * 32 + (lane >> 2);
  const int akk = (lane & 3) * 8;
  auto stageA = [&](int buf, int chunk) {
    const long kb = kb0 + (long)chunk * 32;
    GLD16(A + ((size_t)(b0 + ar))      * KTOT + kb + akk, &As[buf][(wave * 32) * 32]);
    GLD16(A + ((size_t)(b0 + ar + 16)) * KTOT + kb + akk, &As[buf][(wave * 32 + 16) * 32]);
  };

  // B staging: thread -> column n = n0+(tid&127), k-chunk kc = tid>>7 (8 k's)
  const int bn_  = tid & 127;
  const int bkc  = tid >> 7;                 // 0..3
  const float* w1p = W1 + (size_t)(kb0 + bkc * 8) * H_ + n0 + bn_;
  const int b_woff = bn_ * 32 + ((bkc ^ ((bn_ >> 1) & 3)) * 8);

  auto loadB = [&](float* r, int c) {
    const float* p = w1p + (size_t)c * 32 * H_;
    #pragma unroll
    for (int i = 0; i < 8; ++i) r[i] = p[(size_t)i * H_];
  };
  auto writeB = [&](const float* r, ushort* d) {
    uint4 o;
    o.x = (uint)f2bf(r[0]) | ((uint)f2bf(r[1]) << 16);
    o.y = (uint)f2bf(r[2]) | ((uint)f2bf(r[3]) << 16);
    o.z = (uint)f2bf(r[4]) | ((uint)f2bf(r[5]) << 16);
    o.w = (uint)f2bf(r[6]) | ((uint)f2bf(r[7]) << 16);
    *(uint4*)d = o;
  };

  // de-swizzle read offset for frag loads
  const int xo     = (((lane >> 4) ^ ((lane >> 1) & 3)) * 8);
  const int a_roff = (wm * 64 + (lane & 15)) * 32;
  const int b_roff = (wn * 64 + (lane & 15)) * 32;

  float brE[8], brO[8];

#define GITER(c, BRL, BRW, ISSUE, WRITE, VMC) do {                            \
    asm volatile("s_waitcnt vmcnt(" VMC ") lgkmcnt(0)" ::: "memory");         \
    __builtin_amdgcn_s_barrier();                                             \
    __builtin_amdgcn_sched_barrier(0);                                        \
    if (ISSUE) { loadB(BRL, (c) + 2); stageA(((c) + 2) % 3, (c) + 2); }       \
    const ushort* as_ = &As[(c) % 3][a_roff + xo];                            \
    const ushort* bs_ = &Bs[(c) & 1][b_roff + xo];                            \
    short8 af[4], bf[4];                                                      \
    _Pragma("unroll") for (int i = 0; i < 4; ++i) {                           \
      af[i] = *(const short8*)(as_ + i * 16 * 32);                            \
      bf[i] = *(const short8*)(bs_ + i * 16 * 32); }                          \
    _Pragma("unroll") for (int i = 0; i < 4; ++i)                             \
      _Pragma("unroll") for (int j = 0; j < 4; ++j)                           \
        acc[i][j] = __builtin_amdgcn_mfma_f32_16x16x32_bf16(af[i], bf[j],     \
                                                            acc[i][j], 0,0,0);\
    if (WRITE) writeB(BRW, &Bs[((c) + 1) & 1][b_woff]);                       \
  } while (0)

  // prologue: chunks 0,1 in flight; Bs[0] written (compiler inserts vmcnt for brE)
  loadB(brE, 0);
  stageA(0, 0);
  loadB(brO, 1);
  stageA(1, 1);
  writeB(brE, &Bs[0][b_woff]);

  #pragma unroll 1
  for (int cc = 0; cc < 14; cc += 2) {
    GITER(cc,     brE, brO, true, true, "10");
    GITER(cc + 1, brO, brE, true, true, "10");
  }
  GITER(14, brE, brO, true,  true,  "10");
  GITER(15, brO, brE, false, true,  "10");
  GITER(16, brE, brO, false, false, "0");
#undef GITER

  const int row0 = b0 + wm * 64 + (lane >> 4) * 4;
  const int col0 = n0 + wn * 64 + (lane & 15);
  if constexpr (USE_ATOMIC) {
    float* dst = (float*)dstv;
    #pragma unroll
    for (int i = 0; i < 4; ++i)
      #pragma unroll
      for (int j = 0; j < 4; ++j)
        #pragma unroll
        for (int r = 0; r < 4; ++r)
          atomicAdd(&dst[(size_t)(row0 + i * 16 + r) * H_ + col0 + j * 16], acc[i][j][r]);
  } else {
    ushort* P = (ushort*)dstv + (size_t)sk * (B_ * H_);
    #pragma unroll
    for (int i = 0; i < 4; ++i)
      #pragma unroll
      for (int j = 0; j < 4; ++j)
        #pragma unroll
        for (int r = 0; r < 4; ++r)
          P[(size_t)(row0 + i * 16 + r) * H_ + col0 + j * 16] = f2bf(acc[i][j][r]);
  }
}

// ---------------- kernel 3: fused reduce + relu + GEMM2 ----------------
// out[b][v] = b2[v] + sum_n relu(b1[n] + sum_sk P[sk][b][n]) * W2[n][v]
template<bool FROM_PARTIALS>
__global__ __launch_bounds__(256) void gemm2_kernel(
    const void* __restrict__ Pin, const float* __restrict__ b1,
    const float* __restrict__ W2, const float* __restrict__ b2,
    float* __restrict__ out)
{
  const int bb = blockIdx.x * 2;   // 256 blocks, 2 batch rows each
  const int v  = threadIdx.x;      // 0..255
  __shared__ float hs[2][H_];

  // build hs = relu(b1 + sum P) : each thread owns 4 h-elements
  {
    const int id  = v * 4;                 // 0..1020 over 2*512
    const int row = id >> 9, col = id & 511;
    f32x4 s;
    if constexpr (FROM_PARTIALS) {
      const ushort* P = (const ushort*)Pin;
      s = *(const f32x4*)(b1 + col);
      #pragma unroll 4
      for (int sk = 0; sk < SPLITK; ++sk) {
        uint2 u = *(const uint2*)(P + (size_t)sk * (B_ * H_) + (size_t)(bb + row) * H_ + col);
        s[0] += bf2f((ushort)(u.x & 0xffff));
        s[1] += bf2f((ushort)(u.x >> 16));
        s[2] += bf2f((ushort)(u.y & 0xffff));
        s[3] += bf2f((ushort)(u.y >> 16));
      }
    } else {
      s = *(const f32x4*)((const float*)Pin + (size_t)(bb + row) * H_ + col);  // h_pre has b1
    }
    f32x4 r;
    #pragma unroll
    for (int t = 0; t < 4; ++t) r[t] = fmaxf(s[t], 0.f);
    *(f32x4*)&hs[row][col] = r;
  }
  __syncthreads();

  float a0 = 0.f, a1 = 0.f;
  for (int j4 = 0; j4 < H_ / 4; ++j4) {
    f32x4 h0 = *(const f32x4*)&hs[0][j4 * 4];
    f32x4 h1 = *(const f32x4*)&hs[1][j4 * 4];
    #pragma unroll
    for (int t = 0; t < 4; ++t) {
      float w = W2[(size_t)(j4 * 4 + t) * V_ + v];
      a0 += h0[t] * w; a1 += h1[t] * w;
    }
  }
  const float bias = b2[v];
  out[(size_t)(bb + 0) * V_ + v] = a0 + bias;
  out[(size_t)(bb + 1) * V_ + v] = a1 + bias;
}

// ---------------- launch ----------------
extern "C" void kernel_launch(void* const* d_in, const int* in_sizes, int n_in,
                              void* d_out, int out_size, void* d_ws, size_t ws_size,
                              hipStream_t stream) {
  const float* x   = (const float*)d_in[0];
  const float* mem = (const float*)d_in[1];
  const int*   tim = (const int*)d_in[2];
  const float* msu = (const float*)d_in[3];
  const float* W1  = (const float*)d_in[5];
  const float* b1  = (const float*)d_in[6];
  const float* W2  = (const float*)d_in[7];
  const float* b2  = (const float*)d_in[8];
  float* out = (float*)d_out;

  char* ws = (char*)d_ws;
  const size_t abytes = (size_t)B_ * KTOT * 2;          // 35,651,584
  const size_t pbytes = (size_t)SPLITK * B_ * H_ * 2;   // 33,554,432 (bf16 partials)
  const size_t hbytes = (size_t)B_ * H_ * 4;            // 1,048,576
  const bool partials = ws_size >= abytes + pbytes + hbytes;

  ushort* A_ws  = (ushort*)ws;
  void*   P     = (void*)(ws + abytes);
  float*  h_pre = partials ? (float*)(ws + abytes + pbytes)
                           : (float*)(ws + abytes);

  prep_kernel<<<B_, 256, 0, stream>>>(x, mem, tim, msu, b1, A_ws, h_pre);
  if (partials) {
    gemm1_kernel<false><<<8 * SPLITK, 512, 0, stream>>>(A_ws, W1, P);
    gemm2_kernel<true><<<B_ / 2, 256, 0, stream>>>(P, b1, W2, b2, out);
  } else {
    gemm1_kernel<true><<<8 * SPLITK, 512, 0, stream>>>(A_ws, W1, h_pre);
    gemm2_kernel<false><<<B_ / 2, 256, 0, stream>>>(h_pre, b1, W2, b2, out);
  }
}

// Round 8
// 75.015 us; speedup vs baseline: 1.3780x; 1.0165x over previous
//
#include <hip/hip_runtime.h>

typedef unsigned int uint;
typedef unsigned short ushort;
typedef __attribute__((ext_vector_type(8))) short short8;
typedef __attribute__((ext_vector_type(4))) float f32x4;

#define B_   512
#define V_   256
#define M_   128
#define H_   512
#define T_   16
#define KTOT 34816   // V_*M_ + M_*T_

// ---------------- helpers ----------------
__device__ __forceinline__ ushort f2bf(float f) {
  uint u = __builtin_bit_cast(uint, f);
  u += 0x7fffu + ((u >> 16) & 1u);   // RNE
  return (ushort)(u >> 16);
}
__device__ __forceinline__ float bf2f(ushort s) {
  return __builtin_bit_cast(float, ((uint)s) << 16);
}

// sigma-swizzle: within each 32-element (64B) k-group, XOR the 16B-chunk index
// with ((row>>1)&3). A's writer (prep) applies it; gemm1 reads it back.
__device__ __forceinline__ int swz_k(int k, int row) {
  return (k & ~31) | (((((k >> 3) & 3) ^ ((row >> 1) & 3)) << 3)) | (k & 7);
}

// ---------------- kernel 1: per-batch prep ----------------
__global__ __launch_bounds__(256) void prep_kernel(
    const float* __restrict__ x, const float* __restrict__ mem,
    const int* __restrict__ timings, const float* __restrict__ msurp,
    const float* __restrict__ b1,
    ushort* __restrict__ A, float* __restrict__ h_pre)
{
  const int b = blockIdx.x, tid = threadIdx.x;
  __shared__ int s_t[M_];
  __shared__ int s_row[M_];
  __shared__ int s_st[M_];
  __shared__ int s_idx;

  if (tid < 64) {
    float v0 = msurp[b * M_ + tid];
    float v1 = msurp[b * M_ + tid + 64];
    float v; int i;
    if (v1 < v0) { v = v1; i = tid + 64; } else { v = v0; i = tid; }
    #pragma unroll
    for (int off = 32; off > 0; off >>= 1) {
      float ov = __shfl_down(v, off);
      int   oi = __shfl_down(i, off);
      if (ov < v || (ov == v && oi < i)) { v = ov; i = oi; }
    }
    if (tid == 0) s_idx = i;
  }
  __syncthreads();
  const int idx = s_idx;

  if (tid < M_) {
    int t = timings[b * M_ + tid] + 1;
    if (tid == idx) t = 0;
    s_t[tid] = t;
  }
  // h_pre init = b1 (consumed only by the atomic fallback path)
  h_pre[(size_t)b * H_ + tid]       = b1[tid];
  h_pre[(size_t)b * H_ + 256 + tid] = b1[256 + tid];
  __syncthreads();

  if (tid < M_) {
    const int t = s_t[tid];
    int r = 0;
    for (int j = 0; j < M_; ++j) {
      int tj = s_t[j];
      r += (tj < t || (tj == t && j < tid)) ? 1 : 0;
    }
    s_row[r] = tid;   // order[r] = tid
    s_st[r]  = t;     // sorted_t[r]
  }
  __syncthreads();

  // bits region (k >= 32768), swizzled writes
  if (tid < M_) {
    const int t = s_st[tid];
    uint p[8];
    #pragma unroll
    for (int h = 0; h < 8; ++h) {
      uint lo = ((t >> (2 * h)) & 1) ? 0x3F80u : 0u;
      uint hi = ((t >> (2 * h + 1)) & 1) ? 0x3F80u : 0u;
      p[h] = lo | (hi << 16);
    }
    const int k0 = V_ * M_ + tid * T_;
    uint4 w0; w0.x = p[0]; w0.y = p[1]; w0.z = p[2]; w0.w = p[3];
    uint4 w1; w1.x = p[4]; w1.y = p[5]; w1.z = p[6]; w1.w = p[7];
    *(uint4*)(A + (size_t)b * KTOT + swz_k(k0, b))     = w0;
    *(uint4*)(A + (size_t)b * KTOT + swz_k(k0 + 8, b)) = w1;
  }

  // gather rows, swizzled writes (8B pieces stay within one 16B chunk)
  const int lane = tid & 63, sub = tid >> 6;
  for (int it = 0; it < 32; ++it) {
    const int slot = it * 4 + sub;
    const int rowm = s_row[slot];
    const float* src = (rowm == idx) ? (x + (size_t)b * V_)
                                     : (mem + ((size_t)b * M_ + rowm) * V_);
    f32x4 v = *(const f32x4*)(src + lane * 4);
    uint2 o;
    o.x = (uint)f2bf(v[0]) | ((uint)f2bf(v[1]) << 16);
    o.y = (uint)f2bf(v[2]) | ((uint)f2bf(v[3]) << 16);
    const int k = slot * V_ + lane * 4;
    *(uint2*)(A + (size_t)b * KTOT + swz_k(k, b)) = o;
  }
}

// ---------------- kernel 2: split-K bf16 MFMA GEMM, 256x256 tile ----------------
// Traffic-minimal tiling: A(bf16) x2 n-tiles + W1(f32) x2 m-tiles = 214 MB total.
// A: global_load_lds, 3 LDS buffers (depth-2 prefetch).
// B: reg-stage raw f32 W1 (16 strided dwords/thread) -> bf16 -> swizzled ds_write, 2 buffers.
// 18 VMEM ops/iter (2 gld_lds + 16 loadB); entry s_waitcnt vmcnt(18) -> never drains.
#define BM 256
#define BN 256
#define SPLITK 64
#define KCH 544
#define NCHU 17

#define GLD16(g, l) __builtin_amdgcn_global_load_lds( \
  (const __attribute__((address_space(1))) void*)(g), \
  (__attribute__((address_space(3))) void*)(l), 16, 0, 0)

template<bool USE_ATOMIC>
__global__ __launch_bounds__(512, 2) void gemm1_kernel(
    const ushort* __restrict__ A, const float* __restrict__ W1,
    void* __restrict__ dstv)   // fp32 h_pre (atomic) or bf16 partials P[SPLITK][512][512]
{
  __shared__ __align__(16) ushort As[3][BM * 32];   // 48 KB
  __shared__ __align__(16) ushort Bs[2][BN * 32];   // 32 KB

  const int bid  = blockIdx.x;
  // XCD-aligned: same-sk blocks share bid%8 -> same XCD (grid 256 = 4 tiles x 64 sk)
  const int sk   = (bid & 7) | ((bid >> 5) << 3);   // 0..63
  const int tile = (bid >> 3) & 3;                  // 2 m-tiles x 2 n-tiles
  const int b0   = (tile >> 1) * BM;
  const int n0   = (tile & 1) * BN;
  const int tid  = threadIdx.x, wave = tid >> 6, lane = tid & 63;
  const int wm   = wave >> 1;    // 0..3 : 64 rows
  const int wn   = wave & 1;     // 0..1 : 128 cols
  const long kb0 = (long)sk * KCH;

  f32x4 acc[4][8];
  #pragma unroll
  for (int i = 0; i < 4; ++i)
    #pragma unroll
    for (int j = 0; j < 8; ++j) acc[i][j] = (f32x4)0.f;

  // A staging (global_load_lds, linear dest)
  const int ar  = wave * 32 + (lane >> 2);
  const int akk = (lane & 3) * 8;
  auto stageA = [&](int buf, int chunk) {
    const long kb = kb0 + (long)chunk * 32;
    GLD16(A + ((size_t)(b0 + ar))      * KTOT + kb + akk, &As[buf][(wave * 32) * 32]);
    GLD16(A + ((size_t)(b0 + ar + 16)) * KTOT + kb + akk, &As[buf][(wave * 32 + 16) * 32]);
  };

  // B staging: thread -> column n = n0+(tid&255), k-half kh = tid>>8 (16 k's)
  const int ncol = tid & 255;
  const int kh   = tid >> 8;                 // 0..1
  const float* w1p = W1 + (size_t)(kb0 + kh * 16) * H_ + n0 + ncol;
  const int sg   = (ncol >> 1) & 3;
  const int kc0  = kh * 2;
  const int bw0  = ncol * 32 + ((kc0 ^ sg) * 8);
  const int bw1  = ncol * 32 + (((kc0 + 1) ^ sg) * 8);

  auto loadB = [&](float* r, int c) {
    const float* p = w1p + (size_t)c * 32 * H_;
    #pragma unroll
    for (int i = 0; i < 16; ++i) r[i] = p[(size_t)i * H_];
  };
  auto writeB = [&](const float* r, ushort* base) {
    uint4 o0, o1;
    o0.x = (uint)f2bf(r[0])  | ((uint)f2bf(r[1])  << 16);
    o0.y = (uint)f2bf(r[2])  | ((uint)f2bf(r[3])  << 16);
    o0.z = (uint)f2bf(r[4])  | ((uint)f2bf(r[5])  << 16);
    o0.w = (uint)f2bf(r[6])  | ((uint)f2bf(r[7])  << 16);
    o1.x = (uint)f2bf(r[8])  | ((uint)f2bf(r[9])  << 16);
    o1.y = (uint)f2bf(r[10]) | ((uint)f2bf(r[11]) << 16);
    o1.z = (uint)f2bf(r[12]) | ((uint)f2bf(r[13]) << 16);
    o1.w = (uint)f2bf(r[14]) | ((uint)f2bf(r[15]) << 16);
    *(uint4*)(base + bw0) = o0;
    *(uint4*)(base + bw1) = o1;
  };

  // de-swizzle read offset for frag loads
  const int xo     = (((lane >> 4) ^ ((lane >> 1) & 3)) * 8);
  const int a_roff = (wm * 64 + (lane & 15)) * 32;
  const int b_roff = (wn * 128 + (lane & 15)) * 32;

  float brE[16], brO[16];

#define GITER(c, BRL, BRW, ISSUE, WRITE, VMC) do {                            \
    asm volatile("s_waitcnt vmcnt(" VMC ") lgkmcnt(0)" ::: "memory");         \
    __builtin_amdgcn_s_barrier();                                             \
    __builtin_amdgcn_sched_barrier(0);                                        \
    if (ISSUE) { stageA(((c) + 2) % 3, (c) + 2); loadB(BRL, (c) + 2); }       \
    const ushort* as_ = &As[(c) % 3][a_roff + xo];                            \
    const ushort* bs_ = &Bs[(c) & 1][b_roff + xo];                            \
    short8 af[4], bf[4];                                                      \
    _Pragma("unroll") for (int i = 0; i < 4; ++i)                             \
      af[i] = *(const short8*)(as_ + i * 16 * 32);                            \
    _Pragma("unroll") for (int j = 0; j < 4; ++j)                             \
      bf[j] = *(const short8*)(bs_ + j * 16 * 32);                            \
    _Pragma("unroll") for (int i = 0; i < 4; ++i)                             \
      _Pragma("unroll") for (int j = 0; j < 4; ++j)                           \
        acc[i][j] = __builtin_amdgcn_mfma_f32_16x16x32_bf16(af[i], bf[j],     \
                                                            acc[i][j], 0,0,0);\
    _Pragma("unroll") for (int j = 0; j < 4; ++j)                             \
      bf[j] = *(const short8*)(bs_ + (j + 4) * 16 * 32);                      \
    _Pragma("unroll") for (int i = 0; i < 4; ++i)                             \
      _Pragma("unroll") for (int j = 0; j < 4; ++j)                           \
        acc[i][j + 4] = __builtin_amdgcn_mfma_f32_16x16x32_bf16(af[i], bf[j], \
                                                            acc[i][j + 4],    \
                                                            0, 0, 0);         \
    if (WRITE) writeB(BRW, &Bs[((c) + 1) & 1][0]);                            \
  } while (0)

  // prologue: chunks 0,1 in flight; Bs[0] written
  stageA(0, 0);
  loadB(brE, 0);
  stageA(1, 1);
  loadB(brO, 1);
  writeB(brE, &Bs[0][0]);

  #pragma unroll 1
  for (int cc = 0; cc < 14; cc += 2) {
    GITER(cc,     brE, brO, true, true, "18");
    GITER(cc + 1, brO, brE, true, true, "18");
  }
  GITER(14, brE, brO, true,  true,  "18");
  GITER(15, brO, brE, false, true,  "18");
  GITER(16, brE, brO, false, false, "0");
#undef GITER

  const int row0 = b0 + wm * 64 + (lane >> 4) * 4;
  const int col0 = n0 + wn * 128 + (lane & 15);
  if constexpr (USE_ATOMIC) {
    float* dst = (float*)dstv;
    #pragma unroll
    for (int i = 0; i < 4; ++i)
      #pragma unroll
      for (int j = 0; j < 8; ++j)
        #pragma unroll
        for (int r = 0; r < 4; ++r)
          atomicAdd(&dst[(size_t)(row0 + i * 16 + r) * H_ + col0 + j * 16], acc[i][j][r]);
  } else {
    ushort* P = (ushort*)dstv + (size_t)sk * (B_ * H_);
    #pragma unroll
    for (int i = 0; i < 4; ++i)
      #pragma unroll
      for (int j = 0; j < 8; ++j)
        #pragma unroll
        for (int r = 0; r < 4; ++r)
          P[(size_t)(row0 + i * 16 + r) * H_ + col0 + j * 16] = f2bf(acc[i][j][r]);
  }
}

// ---------------- kernel 3: fused reduce + relu + GEMM2 ----------------
// out[b][v] = b2[v] + sum_n relu(b1[n] + sum_sk P[sk][b][n]) * W2[n][v]
template<bool FROM_PARTIALS>
__global__ __launch_bounds__(256) void gemm2_kernel(
    const void* __restrict__ Pin, const float* __restrict__ b1,
    const float* __restrict__ W2, const float* __restrict__ b2,
    float* __restrict__ out)
{
  const int bb = blockIdx.x * 2;   // 256 blocks, 2 batch rows each
  const int v  = threadIdx.x;      // 0..255
  __shared__ float hs[2][H_];

  // build hs = relu(b1 + sum P) : each thread owns 4 h-elements
  {
    const int id  = v * 4;                 // 0..1020 over 2*512
    const int row = id >> 9, col = id & 511;
    f32x4 s;
    if constexpr (FROM_PARTIALS) {
      const ushort* P = (const ushort*)Pin;
      s = *(const f32x4*)(b1 + col);
      #pragma unroll 4
      for (int sk = 0; sk < SPLITK; ++sk) {
        uint2 u = *(const uint2*)(P + (size_t)sk * (B_ * H_) + (size_t)(bb + row) * H_ + col);
        s[0] += bf2f((ushort)(u.x & 0xffff));
        s[1] += bf2f((ushort)(u.x >> 16));
        s[2] += bf2f((ushort)(u.y & 0xffff));
        s[3] += bf2f((ushort)(u.y >> 16));
      }
    } else {
      s = *(const f32x4*)((const float*)Pin + (size_t)(bb + row) * H_ + col);  // h_pre has b1
    }
    f32x4 r;
    #pragma unroll
    for (int t = 0; t < 4; ++t) r[t] = fmaxf(s[t], 0.f);
    *(f32x4*)&hs[row][col] = r;
  }
  __syncthreads();

  float a0 = 0.f, a1 = 0.f;
  for (int j4 = 0; j4 < H_ / 4; ++j4) {
    f32x4 h0 = *(const f32x4*)&hs[0][j4 * 4];
    f32x4 h1 = *(const f32x4*)&hs[1][j4 * 4];
    #pragma unroll
    for (int t = 0; t < 4; ++t) {
      float w = W2[(size_t)(j4 * 4 + t) * V_ + v];
      a0 += h0[t] * w; a1 += h1[t] * w;
    }
  }
  const float bias = b2[v];
  out[(size_t)(bb + 0) * V_ + v] = a0 + bias;
  out[(size_t)(bb + 1) * V_ + v] = a1 + bias;
}

// ---------------- launch ----------------
extern "C" void kernel_launch(void* const* d_in, const int* in_sizes, int n_in,
                              void* d_out, int out_size, void* d_ws, size_t ws_size,
                              hipStream_t stream) {
  const float* x   = (const float*)d_in[0];
  const float* mem = (const float*)d_in[1];
  const int*   tim = (const int*)d_in[2];
  const float* msu = (const float*)d_in[3];
  const float* W1  = (const float*)d_in[5];
  const float* b1  = (const float*)d_in[6];
  const float* W2  = (const float*)d_in[7];
  const float* b2  = (const float*)d_in[8];
  float* out = (float*)d_out;

  char* ws = (char*)d_ws;
  const size_t abytes = (size_t)B_ * KTOT * 2;          // 35,651,584
  const size_t pbytes = (size_t)SPLITK * B_ * H_ * 2;   // 33,554,432 (bf16 partials)
  const size_t hbytes = (size_t)B_ * H_ * 4;            // 1,048,576
  const bool partials = ws_size >= abytes + pbytes + hbytes;

  ushort* A_ws  = (ushort*)ws;
  void*   P     = (void*)(ws + abytes);
  float*  h_pre = partials ? (float*)(ws + abytes + pbytes)
                           : (float*)(ws + abytes);

  prep_kernel<<<B_, 256, 0, stream>>>(x, mem, tim, msu, b1, A_ws, h_pre);
  if (partials) {
    gemm1_kernel<false><<<4 * SPLITK, 512, 0, stream>>>(A_ws, W1, P);
    gemm2_kernel<true><<<B_ / 2, 256, 0, stream>>>(P, b1, W2, b2, out);
  } else {
    gemm1_kernel<true><<<4 * SPLITK, 512, 0, stream>>>(A_ws, W1, h_pre);
    gemm2_kernel<false><<<B_ / 2, 256, 0, stream>>>(h_pre, b1, W2, b2, out);
  }
}